// Round 15
// baseline (68.936 us; speedup 1.0000x reference)
//
#include <hip/hip_runtime.h>
#include <hip/hip_bf16.h>

typedef __attribute__((ext_vector_type(8))) short short8;
typedef __attribute__((ext_vector_type(4))) float f32x4;
typedef __attribute__((ext_vector_type(16))) float f32x16;
typedef __attribute__((ext_vector_type(2))) int int2v;

#define N_TOK 8192
#define D_HALF 64
#define D_FULL 128
#define QB 128                     // q rows per block (4 sub-tiles of 32)
#define KQ 2048                    // keys per block (k-split 4)
#define CHUNK 64                   // keys per chunk (16KB K + 16KB V), quad-buffered
#define NCH (KQ / CHUNK)           // 32
#define OSTR 132
#define RSC 1.2011224087864498f    // sqrt(log2(e)): scores arrive in log2 domain
#define MFIX 94.0f                 // fixed softmax max: > 64*log2(e)=92.33 bound

// Fragment-major layouts (short8 = 16B units):
//   Kf8[(panel*16 + ks*2 + hi)*32 + li]  = K[panel*32+li][ks*16+8*hi .. +8]  (x RSC)
//   Vf8[(kc*4 + dblk)*64 + hi*32 + li]   = V^T[dblk*32+li][kc*16+8*hi .. +8] (raw)
__global__ __launch_bounds__(256) void precompute_kernel(
    const float* __restrict__ mag, const float* __restrict__ phase,
    __hip_bfloat16* __restrict__ Kf, __hip_bfloat16* __restrict__ Vf)
{
    int idx = blockIdx.x * 256 + threadIdx.x;
    if (idx >= N_TOK * D_HALF) return;
    int n = idx >> 6, d0 = idx & 63;
    float m = mag[idx], p = phase[idx];
    float s, c;
    sincosf(p, &s, &c);
    {
        float val[2] = { m * c * RSC, m * s * RSC };
        #pragma unroll
        for (int h = 0; h < 2; ++h) {
            int dc = d0 + 64 * h;
            int off = ((n >> 5) * 16 + (dc >> 4) * 2 + ((dc >> 3) & 1)) * 256
                      + (n & 31) * 8 + (dc & 7);
            Kf[off] = __float2bfloat16(val[h]);
        }
    }
    {
        float val[2] = { m, p };
        #pragma unroll
        for (int h = 0; h < 2; ++h) {
            int dv = d0 + 64 * h;
            int off = ((n >> 4) * 4 + (dv >> 5)) * 512 + ((n >> 3) & 1) * 256
                      + (dv & 31) * 8 + (n & 7);
            Vf[off] = __float2bfloat16(val[h]);
        }
    }
}

// pack two f32 into one bf16x2 word (lo=a, hi=b) -- single v_cvt_pk_bf16_f32
static __device__ __forceinline__ unsigned cvtpk(float a, float b)
{
    unsigned r;
    asm("v_cvt_pk_bf16_f32 %0, %1, %2" : "=v"(r) : "v"(a), "v"(b));
    return r;
}

// T3+T4 port: CHUNK=64 quad-buffer, 3 stages in flight, 2 phases/chunk:
//  ph1: ds_read K -> bar -> lgkm0 -> setprio QK(8 MFMA) -> bar
//  ph2: ds_read V + issue stage(t+3) -> bar -> SM(VALU) -> lgkm0 ->
//       setprio PV(8 MFMA) -> vmcnt(counted) -> bar
// (R14 was the m233-measured 2-phase structural ceiling: 597 TF observed vs
// 607 TF m233; insensitive to VALU cuts. Phase-split is the catalog lever.)
// Fixed-max softmax (bounded scores), merges = pure sums (R14, verified).
__global__ __launch_bounds__(512, 2) void attn_kernel(
    const short8* __restrict__ Kf8, const short8* __restrict__ Vf8,
    float* __restrict__ Opart, float* __restrict__ Sp)
{
    __shared__ __align__(16) char smem[132096];  // 4 x (K 16KB | V 16KB) + merge sums

    const int tid  = threadIdx.x;
    const int wid  = tid >> 6;     // 0..7
    const int lane = tid & 63;
    const int li   = lane & 31;
    const int hi   = lane >> 5;
    const int qh   = wid >> 1;     // q sub-tile 0..3
    const int kp   = wid & 1;      // panel within chunk (1 panel = 32 keys/wave)

    const int bid  = blockIdx.x;
    const int qt   = bid >> 2;     // 0..63
    const int kq   = bid & 3;      // key quarter
    const int rot  = bid & (NCH - 1);

    float (*O_lds)[32][OSTR] = (float (*)[32][OSTR])smem;   // merge reuse (67584B)
    float* s_base = (float*)(smem + 67584);                 // [4][32]
    auto sslot = [&](int slot) -> float* { return s_base + slot * 32; };

    // stage one 64-key chunk (K 16KB + V 16KB): 4 loads/thread
    auto stageKV = [&](int ck, char* lbase) {
        const char* gk = (const char*)(Kf8 + (size_t)ck * 1024);
        const char* gv = (const char*)(Vf8 + (size_t)ck * 1024);
        #pragma unroll
        for (int j = 0; j < 2; ++j)
            __builtin_amdgcn_global_load_lds(
                (const __attribute__((address_space(1))) void*)(gk + j * 8192 + tid * 16),
                (__attribute__((address_space(3))) void*)(lbase + j * 8192 + tid * 16),
                16, 0, 0);
        #pragma unroll
        for (int j = 0; j < 2; ++j)
            __builtin_amdgcn_global_load_lds(
                (const __attribute__((address_space(1))) void*)(gv + j * 8192 + tid * 16),
                (__attribute__((address_space(3))) void*)(lbase + 16384 + j * 8192 + tid * 16),
                16, 0, 0);
    };
    auto ck_of = [&](int t) { return kq * NCH + ((t + rot) & (NCH - 1)); };

    // Q fragments FIRST (oldest in vmcnt queue, so counted waits stay exact)
    short8 bq[8];
    {
        const short8* qp = Kf8 + (size_t)(qt * 4 + qh) * 512;
        #pragma unroll
        for (int ks = 0; ks < 8; ++ks)
            bq[ks] = qp[(ks * 2 + hi) * 32 + li];
    }

    f32x16 acc[4];
    #pragma unroll
    for (int d = 0; d < 4; ++d) acc[d] = (f32x16)(0.0f);
    float srow = 0.0f;

    stageKV(ck_of(0), smem);
    stageKV(ck_of(1), smem + 32768);
    stageKV(ck_of(2), smem + 65536);
    asm volatile("s_waitcnt vmcnt(8)");     // bq + S(0) retired; S(1),S(2) flying
    __builtin_amdgcn_s_barrier();

    for (int t = 0; t < NCH; ++t) {
        char* base = smem + (size_t)(t & 3) * 32768;
        const short8* bK = (const short8*)base;
        const short8* bV = (const short8*)(base + 16384);

        // ---- ph1: ds_read K (in flight across barrier) -> QK cluster ----
        short8 kfr[8];
        #pragma unroll
        for (int ks = 0; ks < 8; ++ks)
            kfr[ks] = bK[kp * 512 + (ks * 2 + hi) * 32 + li];
        __builtin_amdgcn_s_barrier();
        asm volatile("s_waitcnt lgkmcnt(0)" ::: "memory");
        __builtin_amdgcn_sched_barrier(0);
        f32x16 st = (f32x16)(-MFIX);        // C-init folds the softmax subtract
        __builtin_amdgcn_s_setprio(1);
        #pragma unroll
        for (int ks = 0; ks < 8; ++ks)
            st = __builtin_amdgcn_mfma_f32_32x32x16_bf16(kfr[ks], bq[ks], st, 0, 0, 0);
        __builtin_amdgcn_s_setprio(0);
        __builtin_amdgcn_s_barrier();

        // ---- ph2: ds_read V + stage(t+3) -> SM (VALU) -> PV cluster ----
        short8 vfr[8];
        #pragma unroll
        for (int c = 0; c < 2; ++c)
            #pragma unroll
            for (int d = 0; d < 4; ++d)
                vfr[c * 4 + d] = bV[((kp * 2 + c) * 4 + d) * 64 + hi * 32 + li];
        if (t + 3 < NCH)
            stageKV(ck_of(t + 3), smem + (size_t)((t + 3) & 3) * 32768);
        __builtin_amdgcn_s_barrier();

        // softmax (no max machinery): P = exp2(st), row-sum; overlaps V reads
        #pragma unroll
        for (int r = 0; r < 16; ++r) st[r] = exp2f(st[r]);
        float sm[8];
        #pragma unroll
        for (int r = 0; r < 8; ++r) sm[r] = st[r] + st[r + 8];
        float ss = ((sm[0] + sm[1]) + (sm[2] + sm[3]))
                 + ((sm[4] + sm[5]) + (sm[6] + sm[7]));
        srow += ss + __shfl_xor(ss, 32);

        // pack P -> bf16 B-fragments (cvt_pk + permlane32_swap)
        union { int w[4]; short8 v; } u[2];
        #pragma unroll
        for (int c = 0; c < 2; ++c) {
            const int b = 8 * c;
            unsigned a0 = cvtpk(st[b + 0], st[b + 1]);
            unsigned a1 = cvtpk(st[b + 2], st[b + 3]);
            unsigned b0 = cvtpk(st[b + 4], st[b + 5]);
            unsigned b1 = cvtpk(st[b + 6], st[b + 7]);
            int2v r0 = __builtin_amdgcn_permlane32_swap((int)a0, (int)b0, false, false);
            int2v r1 = __builtin_amdgcn_permlane32_swap((int)a1, (int)b1, false, false);
            u[c].w[0] = r0[0]; u[c].w[1] = r1[0]; u[c].w[2] = r0[1]; u[c].w[3] = r1[1];
        }

        asm volatile("s_waitcnt lgkmcnt(0)" ::: "memory");
        __builtin_amdgcn_sched_barrier(0);
        __builtin_amdgcn_s_setprio(1);
        #pragma unroll
        for (int c = 0; c < 2; ++c)
            #pragma unroll
            for (int d = 0; d < 4; ++d)
                acc[d] = __builtin_amdgcn_mfma_f32_32x32x16_bf16(vfr[c * 4 + d], u[c].v, acc[d], 0, 0, 0);
        __builtin_amdgcn_s_setprio(0);

        // counted waits: retire exactly S(t+1) before its chunk begins
        if (t + 3 < NCH)      asm volatile("s_waitcnt vmcnt(8)");
        else if (t + 2 < NCH) asm volatile("s_waitcnt vmcnt(4)");
        else                  asm volatile("s_waitcnt vmcnt(0)");
        __builtin_amdgcn_s_barrier();
    }

    // ---- in-block merge over kp (pure sums) ----
    auto store_partial = [&](int slot) {
        #pragma unroll
        for (int d = 0; d < 4; ++d)
            #pragma unroll
            for (int rr = 0; rr < 4; ++rr) {
                f32x4 v;
                #pragma unroll
                for (int j = 0; j < 4; ++j) v[j] = acc[d][4 * rr + j];
                *reinterpret_cast<f32x4*>(&O_lds[slot][li][d * 32 + 8 * rr + 4 * hi]) = v;
            }
        if (hi == 0) sslot(slot)[li] = srow;
    };
    auto merge_partial = [&](int slot) {
        srow += sslot(slot)[li];
        #pragma unroll
        for (int d = 0; d < 4; ++d)
            #pragma unroll
            for (int rr = 0; rr < 4; ++rr) {
                f32x4 v = *reinterpret_cast<const f32x4*>(&O_lds[slot][li][d * 32 + 8 * rr + 4 * hi]);
                #pragma unroll
                for (int j = 0; j < 4; ++j)
                    acc[d][4 * rr + j] += v[j];
            }
    };

    __syncthreads();                         // staging dead; reuse as merge space
    if (kp == 1) store_partial(qh);
    __syncthreads();
    if (kp == 0) merge_partial(qh);
    __syncthreads();
    if (kp == 0) store_partial(qh);
    __syncthreads();

    // ---- write UNNORMALIZED per-block partial (128 q x 128 d) + merged S ----
    #pragma unroll
    for (int u0 = 0; u0 < 4; ++u0) {
        int u  = tid + u0 * 512;           // 0..2047
        int q  = u >> 4;                   // 0..127
        int dg = (u & 15) * 8;             // 0..120
        int grp = q >> 5, qq = q & 31;
        f32x4 o0 = *reinterpret_cast<const f32x4*>(&O_lds[grp][qq][dg]);
        f32x4 o1 = *reinterpret_cast<const f32x4*>(&O_lds[grp][qq][dg + 4]);
        size_t pidx = (size_t)bid * QB + q;
        *reinterpret_cast<f32x4*>(&Opart[pidx * D_FULL + dg])     = o0;
        *reinterpret_cast<f32x4*>(&Opart[pidx * D_FULL + dg + 4]) = o1;
        if (dg == 0) Sp[pidx] = sslot(grp)[qq];   // merged sum from LDS
    }
}

// combine the four k-quarter partials per q-row (pure sums) and normalize
__global__ __launch_bounds__(256) void merge4_kernel(
    const float* __restrict__ Opart, const float* __restrict__ Sp,
    float* __restrict__ out)
{
    int i   = blockIdx.x * 256 + threadIdx.x;   // 262144 total, 4 floats each
    int row = i >> 5;                           // 0..8191
    int dg  = (i & 31) * 4;                     // 0..124
    int qt  = row >> 7, qq = row & 127;
    size_t pidx[4];
    float S = 0.0f;
    #pragma unroll
    for (int k = 0; k < 4; ++k) {
        pidx[k] = (size_t)(qt * 4 + k) * QB + qq;
        S += Sp[pidx[k]];
    }
    float inv = 1.0f / S;
    f32x4 o = (f32x4)(0.0f);
    #pragma unroll
    for (int k = 0; k < 4; ++k) {
        f32x4 a = *reinterpret_cast<const f32x4*>(&Opart[pidx[k] * D_FULL + dg]);
        #pragma unroll
        for (int j = 0; j < 4; ++j) o[j] += a[j];
    }
    #pragma unroll
    for (int j = 0; j < 4; ++j) o[j] *= inv;
    float* dst = (dg < D_HALF)
        ? out + (size_t)row * D_HALF + dg
        : out + (size_t)N_TOK * D_HALF + (size_t)row * D_HALF + (dg - D_HALF);
    *reinterpret_cast<f32x4*>(dst) = o;
}

extern "C" void kernel_launch(void* const* d_in, const int* in_sizes, int n_in,
                              void* d_out, int out_size, void* d_ws, size_t ws_size,
                              hipStream_t stream)
{
    const float* mag   = (const float*)d_in[0];
    const float* phase = (const float*)d_in[1];
    float* out = (float*)d_out;

    char* ws = (char*)d_ws;
    __hip_bfloat16* Kf = (__hip_bfloat16*)ws;                    // 2 MB
    __hip_bfloat16* Vf = Kf + (size_t)N_TOK * D_FULL;            // 2 MB
    float* Opart = (float*)(ws + 4u * 1024 * 1024);              // 16 MB
    float* Sp    = (float*)(ws + 20u * 1024 * 1024);             // 128 KB

    precompute_kernel<<<(N_TOK * D_HALF + 255) / 256, 256, 0, stream>>>(mag, phase, Kf, Vf);
    attn_kernel<<<256, 512, 0, stream>>>((const short8*)Kf, (const short8*)Vf, Opart, Sp);
    merge4_kernel<<<1024, 256, 0, stream>>>(Opart, Sp, out);
}